// Round 26
// baseline (189.487 us; speedup 1.0000x reference)
//
#include <hip/hip_runtime.h>
#include <math.h>

// No implicit contraction — the projection arithmetic below is bit-frozen
// (verified absmax 0.0 in round 17). Do not change any rounding.
#pragma clang fp contract(off)

#define C_IMG   16
#define C_LIDAR 16
#define IMG_H   376
#define IMG_W   1248
#define HW      (IMG_H * IMG_W)
#define C_OUT   (C_IMG + C_LIDAR)

typedef unsigned int u32;
typedef unsigned long long u64;
typedef float v4f __attribute__((ext_vector_type(4)));

// pack: (valid<<23)|(b<<20)|(vc<<11)|uc
__device__ __forceinline__ u32 project_pack(int4 c4, const float* __restrict__ calib) {
    int b = c4.x, z = c4.y, y = c4.z, x = c4.w;
    // ---- bit-frozen projection (r17-verified) ----
    float px = (float)x * 0.05f;
    float py = (float)y * 0.05f + -25.6f;
    float pz = (float)z * 0.1f  + -2.0f;
    const float* P = calib + b * 12;
    float pr0 = fmaf(P[3], 1.0f, fmaf(P[2], pz, fmaf(P[1], py, fmaf(P[0], px, 0.0f))));
    float pr1 = fmaf(P[7], 1.0f, fmaf(P[6], pz, fmaf(P[5], py, fmaf(P[4], px, 0.0f))));
    float pr2 = fmaf(P[11], 1.0f, fmaf(P[10], pz, fmaf(P[9], py, fmaf(P[8], px, 0.0f))));
    float inv = 1.0f / pr2;    // CR reciprocal (XLA div->mul rewrite)
    float uf = pr0 * inv;      // plain RN mul
    float vf = pr1 * inv;
    int u = (int)uf;
    int v = (int)vf;
    // ---- end bit-frozen section ----
    u32 valid = (u >= 0) & (u < IMG_W) & (v >= 0) & (v < IMG_H);
    int uc = min(max(u, 0), IMG_W - 1);
    int vc = min(max(v, 0), IMG_H - 1);
    return (valid << 23) | ((u32)b << 20) | ((u32)vc << 11) | (u32)uc;
}

// K1: project every voxel, store packed uvb, LDS histogram of (b,row) buckets.
__global__ __launch_bounds__(256) void k1_proj_hist(
    const int* __restrict__ vcoord, const float* __restrict__ calib,
    u32* __restrict__ uvb, u32* __restrict__ hist, int n_vox, int n_buckets)
{
    extern __shared__ u32 lh[];
    for (int i = threadIdx.x; i < n_buckets; i += blockDim.x) lh[i] = 0;
    __syncthreads();

    int n = blockIdx.x * blockDim.x + threadIdx.x;
    if (n < n_vox) {
        int4 c4 = ((const int4*)vcoord)[n];
        u32 p = project_pack(c4, calib);
        uvb[n] = p;
        u32 key = ((p >> 20) & 7) * IMG_H + ((p >> 11) & 0x1FF);
        atomicAdd(&lh[key], 1u);
    }
    __syncthreads();
    for (int i = threadIdx.x; i < n_buckets; i += blockDim.x)
        if (lh[i]) atomicAdd(&hist[i], lh[i]);
}

// K2: exclusive scan of hist -> offs (single block).
__global__ __launch_bounds__(256) void k2_scan(
    const u32* __restrict__ hist, u32* __restrict__ offs, int n_buckets)
{
    __shared__ u32 csum[256];
    int t = threadIdx.x;
    int per = (n_buckets + 255) / 256;
    int lo = t * per, hi = min(lo + per, n_buckets);
    u32 s = 0;
    for (int i = lo; i < hi; ++i) s += hist[i];
    csum[t] = s;
    __syncthreads();
    // inclusive Hillis-Steele scan over csum
    for (int st = 1; st < 256; st <<= 1) {
        u32 v = (t >= st) ? csum[t - st] : 0u;
        __syncthreads();
        csum[t] += v;
        __syncthreads();
    }
    u32 run = (t > 0) ? csum[t - 1] : 0u;
    for (int i = lo; i < hi; ++i) { offs[i] = run; run += hist[i]; }
}

// K3: scatter records (uvb<<32 | n) into bucket-sorted order.
__global__ __launch_bounds__(256) void k3_scatter(
    const u32* __restrict__ uvb, u32* __restrict__ offs,
    u64* __restrict__ recs, int n_vox)
{
    int n = blockIdx.x * blockDim.x + threadIdx.x;
    if (n >= n_vox) return;
    u32 p = uvb[n];
    u32 key = ((p >> 20) & 7) * IMG_H + ((p >> 11) & 0x1FF);
    u32 slot = atomicAdd(&offs[key], 1u);
    recs[slot] = ((u64)p << 32) | (u32)n;
}

// K4: gather in sorted order. 8 lanes/record: lanes 0-3 gather 4 channels
// each from the (B,C,H,W) images; lanes 4-7 copy vfeat. NT out stores.
__global__ __launch_bounds__(256) void k4_gather(
    const u64* __restrict__ recs, const float* __restrict__ images,
    const float* __restrict__ vfeat, float* __restrict__ out, int n_vox)
{
    long long tid = (long long)blockIdx.x * blockDim.x + threadIdx.x;
    int s    = (int)(tid >> 3);
    int lane = (int)(tid & 7);
    if (s >= n_vox) return;

    u64 rec = recs[s];
    int n   = (int)(rec & 0xffffffffu);
    u32 p   = (u32)(rec >> 32);

    v4f* ov = (v4f*)(out + (size_t)n * C_OUT);

    if (lane >= 4) {
        const v4f* vfr = (const v4f*)(vfeat + (size_t)n * C_LIDAR);
        v4f f = vfr[lane - 4];
        __builtin_nontemporal_store(f, &ov[lane]);
        return;
    }

    int uc = p & 0x7FF;
    int vc = (p >> 11) & 0x1FF;
    int b  = (p >> 20) & 7;
    bool valid = (p >> 23) & 1;

    const float* ib = images + (size_t)b * (C_IMG * HW)
                             + (size_t)vc * IMG_W + uc
                             + (size_t)(lane * 4) * HW;
    float g0 = ib[0];
    float g1 = ib[(size_t)1 * HW];
    float g2 = ib[(size_t)2 * HW];
    float g3 = ib[(size_t)3 * HW];

    v4f r;
    r.x = valid ? g0 : 0.0f;
    r.y = valid ? g1 : 0.0f;
    r.z = valid ? g2 : 0.0f;
    r.w = valid ? g3 : 0.0f;
    __builtin_nontemporal_store(r, &ov[lane]);
}

// Fallback: r18 direct gather (no sort) if workspace too small / B too big.
__global__ __launch_bounds__(256) void gather_direct_kernel(
    const float* __restrict__ vfeat, const int* __restrict__ vcoord,
    const float* __restrict__ images, const float* __restrict__ calib,
    float* __restrict__ out, int n_vox)
{
    int tid  = blockIdx.x * blockDim.x + threadIdx.x;
    int s    = tid >> 3;
    int lane = tid & 7;
    if (s >= n_vox) return;

    float4* ov = (float4*)(out + (size_t)s * C_OUT);
    if (lane >= 4) {
        const float4* vfr = (const float4*)(vfeat + (size_t)s * C_LIDAR);
        ov[lane] = vfr[lane - 4];
        return;
    }
    int4 c4 = ((const int4*)vcoord)[s];
    u32 p = project_pack(c4, calib);
    int uc = p & 0x7FF, vc = (p >> 11) & 0x1FF, b = (p >> 20) & 7;
    bool valid = (p >> 23) & 1;

    const float* ib = images + (size_t)b * (C_IMG * HW)
                             + (size_t)vc * IMG_W + uc
                             + (size_t)(lane * 4) * HW;
    float g0 = ib[0];
    float g1 = ib[(size_t)1 * HW];
    float g2 = ib[(size_t)2 * HW];
    float g3 = ib[(size_t)3 * HW];

    float4 r;
    r.x = valid ? g0 : 0.0f;
    r.y = valid ? g1 : 0.0f;
    r.z = valid ? g2 : 0.0f;
    r.w = valid ? g3 : 0.0f;
    ov[lane] = r;
}

extern "C" void kernel_launch(void* const* d_in, const int* in_sizes, int n_in,
                              void* d_out, int out_size, void* d_ws, size_t ws_size,
                              hipStream_t stream) {
    const float* vfeat  = (const float*)d_in[0];
    const int*   vcoord = (const int*)d_in[1];
    const float* images = (const float*)d_in[2];
    const float* calib  = (const float*)d_in[3];
    float* out = (float*)d_out;

    int n_vox = in_sizes[1] / 4;                  // voxel_coords is (N, 4)
    int B     = in_sizes[2] / (C_IMG * HW);       // batch
    int n_buckets = B * IMG_H;                    // (b, row) buckets

    // ws layout: uvb[n_vox] u32 | hist[nb] u32 | offs[nb] u32 | recs[n_vox] u64
    size_t off_uvb  = 0;
    size_t off_hist = off_uvb  + (size_t)n_vox * 4;
    size_t off_offs = off_hist + (size_t)n_buckets * 4;
    size_t off_recs = (off_offs + (size_t)n_buckets * 4 + 7) & ~(size_t)7;
    size_t ws_needed = off_recs + (size_t)n_vox * 8;

    dim3 block(256);
    long long total8 = (long long)n_vox * 8;
    dim3 ggrid((unsigned)((total8 + 255) / 256));

    if (ws_size >= ws_needed && B <= 8) {
        char* wsb = (char*)d_ws;
        u32* uvb  = (u32*)(wsb + off_uvb);
        u32* hist = (u32*)(wsb + off_hist);
        u32* offs = (u32*)(wsb + off_offs);
        u64* recs = (u64*)(wsb + off_recs);

        hipMemsetAsync(hist, 0, (size_t)n_buckets * 4, stream);

        dim3 vgrid((unsigned)((n_vox + 255) / 256));
        size_t lds_hist = (size_t)n_buckets * 4;
        k1_proj_hist<<<vgrid, block, lds_hist, stream>>>(vcoord, calib, uvb, hist, n_vox, n_buckets);
        k2_scan<<<dim3(1), block, 0, stream>>>(hist, offs, n_buckets);
        k3_scatter<<<vgrid, block, 0, stream>>>(uvb, offs, recs, n_vox);
        k4_gather<<<ggrid, block, 0, stream>>>(recs, images, vfeat, out, n_vox);
    } else {
        gather_direct_kernel<<<ggrid, block, 0, stream>>>(vfeat, vcoord, images, calib, out, n_vox);
    }
}

// Round 27
// 115.648 us; speedup vs baseline: 1.6385x; 1.6385x over previous
//
#include <hip/hip_runtime.h>
#include <math.h>

// No implicit contraction — the projection arithmetic below is bit-frozen
// (verified absmax 0.0 in round 17). Do not change any rounding.
#pragma clang fp contract(off)

#define C_IMG   16
#define C_LIDAR 16
#define IMG_H   376
#define IMG_W   1248
#define HW      (IMG_H * IMG_W)
#define C_OUT   (C_IMG + C_LIDAR)
#define NB_MAX  3009            // 8*376 valid buckets + 1 invalid bucket

typedef unsigned int u32;
typedef unsigned long long u64;
typedef float v4f __attribute__((ext_vector_type(4)));

// pack: (valid<<23)|(b<<20)|(vc<<11)|uc
__device__ __forceinline__ u32 project_pack(int4 c4, const float* __restrict__ calib) {
    int b = c4.x, z = c4.y, y = c4.z, x = c4.w;
    // ---- bit-frozen projection (r17-verified) ----
    float px = (float)x * 0.05f;
    float py = (float)y * 0.05f + -25.6f;
    float pz = (float)z * 0.1f  + -2.0f;
    const float* P = calib + b * 12;
    float pr0 = fmaf(P[3], 1.0f, fmaf(P[2], pz, fmaf(P[1], py, fmaf(P[0], px, 0.0f))));
    float pr1 = fmaf(P[7], 1.0f, fmaf(P[6], pz, fmaf(P[5], py, fmaf(P[4], px, 0.0f))));
    float pr2 = fmaf(P[11], 1.0f, fmaf(P[10], pz, fmaf(P[9], py, fmaf(P[8], px, 0.0f))));
    float inv = 1.0f / pr2;    // CR reciprocal (XLA div->mul rewrite)
    float uf = pr0 * inv;      // plain RN mul
    float vf = pr1 * inv;
    int u = (int)uf;
    int v = (int)vf;
    // ---- end bit-frozen section ----
    u32 valid = (u >= 0) & (u < IMG_W) & (v >= 0) & (v < IMG_H);
    int uc = min(max(u, 0), IMG_W - 1);
    int vc = min(max(v, 0), IMG_H - 1);
    return (valid << 23) | ((u32)b << 20) | ((u32)vc << 11) | (u32)uc;
}

__device__ __forceinline__ u32 bucket_of(u32 p, int nb_valid) {
    u32 valid = (p >> 23) & 1;
    u32 key = ((p >> 20) & 7) * IMG_H + ((p >> 11) & 0x1FF);
    return valid ? key : (u32)nb_valid;   // invalids -> dedicated last bucket
}

// K1: project every voxel, store packed uvb, LDS histogram of buckets.
__global__ __launch_bounds__(256) void k1_proj_hist(
    const int* __restrict__ vcoord, const float* __restrict__ calib,
    u32* __restrict__ uvb, u32* __restrict__ hist, int n_vox, int n_buckets)
{
    extern __shared__ u32 lh[];
    for (int i = threadIdx.x; i < n_buckets; i += blockDim.x) lh[i] = 0;
    __syncthreads();

    int n = blockIdx.x * blockDim.x + threadIdx.x;
    if (n < n_vox) {
        int4 c4 = ((const int4*)vcoord)[n];
        u32 p = project_pack(c4, calib);
        uvb[n] = p;
        atomicAdd(&lh[bucket_of(p, n_buckets - 1)], 1u);
    }
    __syncthreads();
    for (int i = threadIdx.x; i < n_buckets; i += blockDim.x)
        if (lh[i]) atomicAdd(&hist[i], lh[i]);
}

// K2: exclusive scan of hist -> offs (single block).
__global__ __launch_bounds__(256) void k2_scan(
    const u32* __restrict__ hist, u32* __restrict__ offs, int n_buckets)
{
    __shared__ u32 csum[256];
    int t = threadIdx.x;
    int per = (n_buckets + 255) / 256;
    int lo = t * per, hi = min(lo + per, n_buckets);
    u32 s = 0;
    for (int i = lo; i < hi; ++i) s += hist[i];
    csum[t] = s;
    __syncthreads();
    for (int st = 1; st < 256; st <<= 1) {
        u32 v = (t >= st) ? csum[t - st] : 0u;
        __syncthreads();
        csum[t] += v;
        __syncthreads();
    }
    u32 run = (t > 0) ? csum[t - 1] : 0u;
    for (int i = lo; i < hi; ++i) { offs[i] = run; run += hist[i]; }
}

// K3: LDS-aggregated scatter — one global atomic per (block,bucket), so
// same-address chains are <=1172 (pipelined), not 20k+ (r26's 101us bug).
__global__ __launch_bounds__(256) void k3_scatter(
    const u32* __restrict__ uvb, u32* __restrict__ offs,
    u64* __restrict__ recs, int n_vox, int n_buckets)
{
    __shared__ u32 cnt[NB_MAX];
    __shared__ u32 base[NB_MAX];

    for (int i = threadIdx.x; i < n_buckets; i += blockDim.x) cnt[i] = 0;
    __syncthreads();

    int n = blockIdx.x * blockDim.x + threadIdx.x;
    u32 p = 0, key = 0, rank = 0;
    bool live = n < n_vox;
    if (live) {
        p = uvb[n];
        key = bucket_of(p, n_buckets - 1);
        rank = atomicAdd(&cnt[key], 1u);     // LDS atomic: intra-block rank
    }
    __syncthreads();
    for (int i = threadIdx.x; i < n_buckets; i += blockDim.x)
        if (cnt[i]) base[i] = atomicAdd(&offs[i], cnt[i]);  // range reserve
    __syncthreads();
    if (live)
        recs[base[key] + rank] = ((u64)p << 32) | (u32)n;
}

// K4: gather in sorted order. 8 lanes/record: lanes 0-3 gather 4 channels
// each; lanes 4-7 copy vfeat. XCD-swizzled blocks keep each row's line set
// in one XCD's L2. NT out stores (out never re-read).
__global__ __launch_bounds__(256) void k4_gather(
    const u64* __restrict__ recs, const float* __restrict__ images,
    const float* __restrict__ vfeat, float* __restrict__ out,
    int n_vox, int nwg)
{
    // bijective XCD swizzle (m204): consecutive content -> same XCD
    int orig = blockIdx.x;
    int xcd = orig % 8, loc = orig / 8;
    int q = nwg / 8, r = nwg % 8;
    int wg = (xcd < r ? xcd * (q + 1) : r * (q + 1) + (xcd - r) * q) + loc;

    long long tid = (long long)wg * blockDim.x + threadIdx.x;
    int s    = (int)(tid >> 3);
    int lane = (int)(tid & 7);
    if (s >= n_vox) return;

    u64 rec = recs[s];
    int n   = (int)(rec & 0xffffffffu);
    u32 p   = (u32)(rec >> 32);

    v4f* ov = (v4f*)(out + (size_t)n * C_OUT);

    if (lane >= 4) {
        const v4f* vfr = (const v4f*)(vfeat + (size_t)n * C_LIDAR);
        v4f f = vfr[lane - 4];
        __builtin_nontemporal_store(f, &ov[lane]);
        return;
    }

    bool valid = (p >> 23) & 1;
    v4f rv = {0.0f, 0.0f, 0.0f, 0.0f};
    if (valid) {
        int uc = p & 0x7FF;
        int vc = (p >> 11) & 0x1FF;
        int b  = (p >> 20) & 7;
        const float* ib = images + (size_t)b * (C_IMG * HW)
                                 + (size_t)vc * IMG_W + uc
                                 + (size_t)(lane * 4) * HW;
        rv.x = ib[0];
        rv.y = ib[(size_t)1 * HW];
        rv.z = ib[(size_t)2 * HW];
        rv.w = ib[(size_t)3 * HW];
    }
    __builtin_nontemporal_store(rv, &ov[lane]);
}

// Fallback: direct gather (no sort) if workspace too small / B too big.
__global__ __launch_bounds__(256) void gather_direct_kernel(
    const float* __restrict__ vfeat, const int* __restrict__ vcoord,
    const float* __restrict__ images, const float* __restrict__ calib,
    float* __restrict__ out, int n_vox)
{
    int tid  = blockIdx.x * blockDim.x + threadIdx.x;
    int s    = tid >> 3;
    int lane = tid & 7;
    if (s >= n_vox) return;

    float4* ov = (float4*)(out + (size_t)s * C_OUT);
    if (lane >= 4) {
        const float4* vfr = (const float4*)(vfeat + (size_t)s * C_LIDAR);
        ov[lane] = vfr[lane - 4];
        return;
    }
    int4 c4 = ((const int4*)vcoord)[s];
    u32 p = project_pack(c4, calib);
    int uc = p & 0x7FF, vc = (p >> 11) & 0x1FF, b = (p >> 20) & 7;
    bool valid = (p >> 23) & 1;

    const float* ib = images + (size_t)b * (C_IMG * HW)
                             + (size_t)vc * IMG_W + uc
                             + (size_t)(lane * 4) * HW;
    float g0 = ib[0];
    float g1 = ib[(size_t)1 * HW];
    float g2 = ib[(size_t)2 * HW];
    float g3 = ib[(size_t)3 * HW];

    float4 r;
    r.x = valid ? g0 : 0.0f;
    r.y = valid ? g1 : 0.0f;
    r.z = valid ? g2 : 0.0f;
    r.w = valid ? g3 : 0.0f;
    ov[lane] = r;
}

extern "C" void kernel_launch(void* const* d_in, const int* in_sizes, int n_in,
                              void* d_out, int out_size, void* d_ws, size_t ws_size,
                              hipStream_t stream) {
    const float* vfeat  = (const float*)d_in[0];
    const int*   vcoord = (const int*)d_in[1];
    const float* images = (const float*)d_in[2];
    const float* calib  = (const float*)d_in[3];
    float* out = (float*)d_out;

    int n_vox = in_sizes[1] / 4;                  // voxel_coords is (N, 4)
    int B     = in_sizes[2] / (C_IMG * HW);       // batch
    int n_buckets = B * IMG_H + 1;                // + invalid bucket

    // ws layout: uvb[n_vox] u32 | hist[nb] u32 | offs[nb] u32 | recs[n_vox] u64
    size_t off_uvb  = 0;
    size_t off_hist = off_uvb  + (size_t)n_vox * 4;
    size_t off_offs = off_hist + (size_t)n_buckets * 4;
    size_t off_recs = (off_offs + (size_t)n_buckets * 4 + 7) & ~(size_t)7;
    size_t ws_needed = off_recs + (size_t)n_vox * 8;

    dim3 block(256);
    long long total8 = (long long)n_vox * 8;
    int ggrid = (int)((total8 + 255) / 256);

    if (ws_size >= ws_needed && B <= 8 && n_buckets <= NB_MAX) {
        char* wsb = (char*)d_ws;
        u32* uvb  = (u32*)(wsb + off_uvb);
        u32* hist = (u32*)(wsb + off_hist);
        u32* offs = (u32*)(wsb + off_offs);
        u64* recs = (u64*)(wsb + off_recs);

        hipMemsetAsync(hist, 0, (size_t)n_buckets * 4, stream);

        dim3 vgrid((unsigned)((n_vox + 255) / 256));
        size_t lds_hist = (size_t)n_buckets * 4;
        k1_proj_hist<<<vgrid, block, lds_hist, stream>>>(vcoord, calib, uvb, hist, n_vox, n_buckets);
        k2_scan<<<dim3(1), block, 0, stream>>>(hist, offs, n_buckets);
        k3_scatter<<<vgrid, block, 0, stream>>>(uvb, offs, recs, n_vox, n_buckets);
        k4_gather<<<dim3((unsigned)ggrid), block, 0, stream>>>(recs, images, vfeat, out, n_vox, ggrid);
    } else {
        gather_direct_kernel<<<dim3((unsigned)ggrid), block, 0, stream>>>(vfeat, vcoord, images, calib, out, n_vox);
    }
}

// Round 28
// 112.593 us; speedup vs baseline: 1.6829x; 1.0271x over previous
//
#include <hip/hip_runtime.h>
#include <math.h>

// No implicit contraction — the projection arithmetic below is bit-frozen
// (verified absmax 0.0 in round 17). Do not change any rounding.
#pragma clang fp contract(off)

#define C_IMG   16
#define C_LIDAR 16
#define IMG_H   376
#define IMG_W   1248
#define HW      (IMG_H * IMG_W)
#define C_OUT   (C_IMG + C_LIDAR)
#define NB_MAX  3009            // 8*376 valid buckets + 1 invalid bucket

typedef unsigned int u32;
typedef unsigned long long u64;
typedef float v4f __attribute__((ext_vector_type(4)));

// pack: (valid<<23)|(b<<20)|(vc<<11)|uc
__device__ __forceinline__ u32 project_pack(int4 c4, const float* __restrict__ calib) {
    int b = c4.x, z = c4.y, y = c4.z, x = c4.w;
    // ---- bit-frozen projection (r17-verified) ----
    float px = (float)x * 0.05f;
    float py = (float)y * 0.05f + -25.6f;
    float pz = (float)z * 0.1f  + -2.0f;
    const float* P = calib + b * 12;
    float pr0 = fmaf(P[3], 1.0f, fmaf(P[2], pz, fmaf(P[1], py, fmaf(P[0], px, 0.0f))));
    float pr1 = fmaf(P[7], 1.0f, fmaf(P[6], pz, fmaf(P[5], py, fmaf(P[4], px, 0.0f))));
    float pr2 = fmaf(P[11], 1.0f, fmaf(P[10], pz, fmaf(P[9], py, fmaf(P[8], px, 0.0f))));
    float inv = 1.0f / pr2;    // CR reciprocal (XLA div->mul rewrite)
    float uf = pr0 * inv;      // plain RN mul
    float vf = pr1 * inv;
    int u = (int)uf;
    int v = (int)vf;
    // ---- end bit-frozen section ----
    u32 valid = (u >= 0) & (u < IMG_W) & (v >= 0) & (v < IMG_H);
    int uc = min(max(u, 0), IMG_W - 1);
    int vc = min(max(v, 0), IMG_H - 1);
    return (valid << 23) | ((u32)b << 20) | ((u32)vc << 11) | (u32)uc;
}

__device__ __forceinline__ u32 bucket_of(u32 p, int nb_valid) {
    u32 valid = (p >> 23) & 1;
    u32 key = ((p >> 20) & 7) * IMG_H + ((p >> 11) & 0x1FF);
    return valid ? key : (u32)nb_valid;   // invalids -> dedicated last bucket
}

// K0: zero the histogram (r27 lesson: hipMemsetAsync of 12KB costs ~69us!).
__global__ __launch_bounds__(256) void k0_zero(u32* __restrict__ hist, int n_buckets)
{
    int i = blockIdx.x * blockDim.x + threadIdx.x;
    if (i < n_buckets) hist[i] = 0;
}

// K1: project every voxel, store packed uvb, LDS histogram of buckets.
__global__ __launch_bounds__(256) void k1_proj_hist(
    const int* __restrict__ vcoord, const float* __restrict__ calib,
    u32* __restrict__ uvb, u32* __restrict__ hist, int n_vox, int n_buckets)
{
    extern __shared__ u32 lh[];
    for (int i = threadIdx.x; i < n_buckets; i += blockDim.x) lh[i] = 0;
    __syncthreads();

    int n = blockIdx.x * blockDim.x + threadIdx.x;
    if (n < n_vox) {
        int4 c4 = ((const int4*)vcoord)[n];
        u32 p = project_pack(c4, calib);
        uvb[n] = p;
        atomicAdd(&lh[bucket_of(p, n_buckets - 1)], 1u);
    }
    __syncthreads();
    for (int i = threadIdx.x; i < n_buckets; i += blockDim.x)
        if (lh[i]) atomicAdd(&hist[i], lh[i]);
}

// K2: exclusive scan of hist -> offs (single block).
__global__ __launch_bounds__(256) void k2_scan(
    const u32* __restrict__ hist, u32* __restrict__ offs, int n_buckets)
{
    __shared__ u32 csum[256];
    int t = threadIdx.x;
    int per = (n_buckets + 255) / 256;
    int lo = t * per, hi = min(lo + per, n_buckets);
    u32 s = 0;
    for (int i = lo; i < hi; ++i) s += hist[i];
    csum[t] = s;
    __syncthreads();
    for (int st = 1; st < 256; st <<= 1) {
        u32 v = (t >= st) ? csum[t - st] : 0u;
        __syncthreads();
        csum[t] += v;
        __syncthreads();
    }
    u32 run = (t > 0) ? csum[t - 1] : 0u;
    for (int i = lo; i < hi; ++i) { offs[i] = run; run += hist[i]; }
}

// K3: LDS-aggregated scatter — one global atomic per (block,bucket).
__global__ __launch_bounds__(256) void k3_scatter(
    const u32* __restrict__ uvb, u32* __restrict__ offs,
    u64* __restrict__ recs, int n_vox, int n_buckets)
{
    __shared__ u32 cnt[NB_MAX];
    __shared__ u32 base[NB_MAX];

    for (int i = threadIdx.x; i < n_buckets; i += blockDim.x) cnt[i] = 0;
    __syncthreads();

    int n = blockIdx.x * blockDim.x + threadIdx.x;
    u32 p = 0, key = 0, rank = 0;
    bool live = n < n_vox;
    if (live) {
        p = uvb[n];
        key = bucket_of(p, n_buckets - 1);
        rank = atomicAdd(&cnt[key], 1u);     // LDS atomic: intra-block rank
    }
    __syncthreads();
    for (int i = threadIdx.x; i < n_buckets; i += blockDim.x)
        if (cnt[i]) base[i] = atomicAdd(&offs[i], cnt[i]);  // range reserve
    __syncthreads();
    if (live)
        recs[base[key] + rank] = ((u64)p << 32) | (u32)n;
}

// K4: gather in sorted order. 8 lanes/record: lanes 0-3 gather 4 channels
// each; lanes 4-7 copy vfeat. XCD-swizzled blocks keep each row's line set
// in one XCD's L2. NT out stores (out never re-read).
__global__ __launch_bounds__(256) void k4_gather(
    const u64* __restrict__ recs, const float* __restrict__ images,
    const float* __restrict__ vfeat, float* __restrict__ out,
    int n_vox, int nwg)
{
    // bijective XCD swizzle (m204): consecutive content -> same XCD
    int orig = blockIdx.x;
    int xcd = orig % 8, loc = orig / 8;
    int q = nwg / 8, r = nwg % 8;
    int wg = (xcd < r ? xcd * (q + 1) : r * (q + 1) + (xcd - r) * q) + loc;

    long long tid = (long long)wg * blockDim.x + threadIdx.x;
    int s    = (int)(tid >> 3);
    int lane = (int)(tid & 7);
    if (s >= n_vox) return;

    u64 rec = recs[s];
    int n   = (int)(rec & 0xffffffffu);
    u32 p   = (u32)(rec >> 32);

    v4f* ov = (v4f*)(out + (size_t)n * C_OUT);

    if (lane >= 4) {
        const v4f* vfr = (const v4f*)(vfeat + (size_t)n * C_LIDAR);
        v4f f = vfr[lane - 4];
        __builtin_nontemporal_store(f, &ov[lane]);
        return;
    }

    bool valid = (p >> 23) & 1;
    v4f rv = {0.0f, 0.0f, 0.0f, 0.0f};
    if (valid) {
        int uc = p & 0x7FF;
        int vc = (p >> 11) & 0x1FF;
        int b  = (p >> 20) & 7;
        const float* ib = images + (size_t)b * (C_IMG * HW)
                                 + (size_t)vc * IMG_W + uc
                                 + (size_t)(lane * 4) * HW;
        rv.x = ib[0];
        rv.y = ib[(size_t)1 * HW];
        rv.z = ib[(size_t)2 * HW];
        rv.w = ib[(size_t)3 * HW];
    }
    __builtin_nontemporal_store(rv, &ov[lane]);
}

// Fallback: direct gather (no sort) if workspace too small / B too big.
__global__ __launch_bounds__(256) void gather_direct_kernel(
    const float* __restrict__ vfeat, const int* __restrict__ vcoord,
    const float* __restrict__ images, const float* __restrict__ calib,
    float* __restrict__ out, int n_vox)
{
    int tid  = blockIdx.x * blockDim.x + threadIdx.x;
    int s    = tid >> 3;
    int lane = tid & 7;
    if (s >= n_vox) return;

    float4* ov = (float4*)(out + (size_t)s * C_OUT);
    if (lane >= 4) {
        const float4* vfr = (const float4*)(vfeat + (size_t)s * C_LIDAR);
        ov[lane] = vfr[lane - 4];
        return;
    }
    int4 c4 = ((const int4*)vcoord)[s];
    u32 p = project_pack(c4, calib);
    int uc = p & 0x7FF, vc = (p >> 11) & 0x1FF, b = (p >> 20) & 7;
    bool valid = (p >> 23) & 1;

    const float* ib = images + (size_t)b * (C_IMG * HW)
                             + (size_t)vc * IMG_W + uc
                             + (size_t)(lane * 4) * HW;
    float g0 = ib[0];
    float g1 = ib[(size_t)1 * HW];
    float g2 = ib[(size_t)2 * HW];
    float g3 = ib[(size_t)3 * HW];

    float4 r;
    r.x = valid ? g0 : 0.0f;
    r.y = valid ? g1 : 0.0f;
    r.z = valid ? g2 : 0.0f;
    r.w = valid ? g3 : 0.0f;
    ov[lane] = r;
}

extern "C" void kernel_launch(void* const* d_in, const int* in_sizes, int n_in,
                              void* d_out, int out_size, void* d_ws, size_t ws_size,
                              hipStream_t stream) {
    const float* vfeat  = (const float*)d_in[0];
    const int*   vcoord = (const int*)d_in[1];
    const float* images = (const float*)d_in[2];
    const float* calib  = (const float*)d_in[3];
    float* out = (float*)d_out;

    int n_vox = in_sizes[1] / 4;                  // voxel_coords is (N, 4)
    int B     = in_sizes[2] / (C_IMG * HW);       // batch
    int n_buckets = B * IMG_H + 1;                // + invalid bucket

    // ws layout: uvb[n_vox] u32 | hist[nb] u32 | offs[nb] u32 | recs[n_vox] u64
    size_t off_uvb  = 0;
    size_t off_hist = off_uvb  + (size_t)n_vox * 4;
    size_t off_offs = off_hist + (size_t)n_buckets * 4;
    size_t off_recs = (off_offs + (size_t)n_buckets * 4 + 7) & ~(size_t)7;
    size_t ws_needed = off_recs + (size_t)n_vox * 8;

    dim3 block(256);
    long long total8 = (long long)n_vox * 8;
    int ggrid = (int)((total8 + 255) / 256);

    if (ws_size >= ws_needed && B <= 8 && n_buckets <= NB_MAX) {
        char* wsb = (char*)d_ws;
        u32* uvb  = (u32*)(wsb + off_uvb);
        u32* hist = (u32*)(wsb + off_hist);
        u32* offs = (u32*)(wsb + off_offs);
        u64* recs = (u64*)(wsb + off_recs);

        dim3 vgrid((unsigned)((n_vox + 255) / 256));
        size_t lds_hist = (size_t)n_buckets * 4;
        k0_zero<<<dim3((unsigned)((n_buckets + 255) / 256)), block, 0, stream>>>(hist, n_buckets);
        k1_proj_hist<<<vgrid, block, lds_hist, stream>>>(vcoord, calib, uvb, hist, n_vox, n_buckets);
        k2_scan<<<dim3(1), block, 0, stream>>>(hist, offs, n_buckets);
        k3_scatter<<<vgrid, block, 0, stream>>>(uvb, offs, recs, n_vox, n_buckets);
        k4_gather<<<dim3((unsigned)ggrid), block, 0, stream>>>(recs, images, vfeat, out, n_vox, ggrid);
    } else {
        gather_direct_kernel<<<dim3((unsigned)ggrid), block, 0, stream>>>(vfeat, vcoord, images, calib, out, n_vox);
    }
}

// Round 29
// 61.660 us; speedup vs baseline: 3.0731x; 1.8260x over previous
//
#include <hip/hip_runtime.h>
#include <math.h>

// No implicit contraction — the projection arithmetic below is bit-frozen
// (verified absmax 0.0 in round 17). Do not change any rounding.
#pragma clang fp contract(off)

#define C_IMG   16
#define C_LIDAR 16
#define IMG_H   376
#define IMG_W   1248
#define HW      (IMG_H * IMG_W)
#define C_OUT   (C_IMG + C_LIDAR)
#define TPIX    64               // pixels per wave-tile; HW % 64 == 0
#define LROW    (TPIX + 2)       // +2 pad: stage/drain aliasing <=2-way (free)

typedef float v4f __attribute__((ext_vector_type(4)));
typedef const __attribute__((address_space(1))) unsigned int glb_u32;
typedef __attribute__((address_space(3))) unsigned int lds_u32;

// Pass 1: (B,C,H,W) -> (B,H,W,C) via small LDS tiles.
// Staging: async global->LDS DMA (global_load_lds width=4) — per-lane global
// src, wave-uniform LDS base + lane*4 matches lds[wv][c][lane] exactly.
// Drain: unit-stride NONTEMPORAL float4 stores (exact-line merging, no L3
// allocation — ws is read-once; keeps the 120MB image set L3-resident).
__global__ __launch_bounds__(256) void transpose_lds_kernel(
    const float* __restrict__ images,   // (B, 16, H, W)
    float*       __restrict__ ws,       // (B, H, W, 16)
    int tiles_total)                    // B*HW / TPIX
{
    __shared__ float lds[4][C_IMG][LROW];   // 4 waves x 4.2KB = 16.9KB/block

    int wv   = threadIdx.x >> 6;
    int lane = threadIdx.x & 63;
    int tile = blockIdx.x * 4 + wv;
    if (tile >= tiles_total) return;

    long long pixbase = (long long)tile * TPIX;  // batch-aligned: HW%TPIX==0
    int b   = (int)(pixbase / HW);
    int pix = (int)(pixbase - (long long)b * HW);

    const float* src = images + (size_t)b * (C_IMG * HW) + pix + lane;

    // stage: 16 async DMA issues, no VGPR round-trip
    #pragma unroll
    for (int c = 0; c < C_IMG; ++c) {
        __builtin_amdgcn_global_load_lds(
            (glb_u32*)(src + (size_t)c * HW),
            (lds_u32*)&lds[wv][c][0],
            4, 0, 0);
    }
    asm volatile("s_waitcnt vmcnt(0)" ::: "memory");
    __builtin_amdgcn_sched_barrier(0);

    // drain: float4 slot s = k*64+lane; pixel p = s>>2, quad q = s&3;
    // unit-stride nontemporal stores.
    v4f* dst = (v4f*)(ws + (size_t)pixbase * C_IMG);
    #pragma unroll
    for (int k = 0; k < (TPIX * 4 / 64); ++k) {   // 4 iterations
        int s = k * 64 + lane;
        int p = s >> 2;
        int q = s & 3;
        v4f o;
        o.x = lds[wv][4 * q + 0][p];
        o.y = lds[wv][4 * q + 1][p];
        o.z = lds[wv][4 * q + 2][p];
        o.w = lds[wv][4 * q + 3][p];
        __builtin_nontemporal_store(o, &dst[s]);
    }
}

// Pass 2: 8 threads per voxel; lanes 0-3 read one v4f each of the SAME 64B
// pixel line from ws (nt loads: read-once); lanes 4-7 copy vfeat.
// out stores nontemporal (never re-read).
__global__ __launch_bounds__(256) void gather_kernel(
    const float* __restrict__ vfeat,    // (N, 16)
    const int*   __restrict__ vcoord,   // (N, 4)  [b, z, y, x]
    const float* __restrict__ ws,       // (B, H, W, 16)
    const float* __restrict__ calib,    // (B, 3, 4)
    float*       __restrict__ out,      // (N, 32)
    int n_vox)
{
    int tid  = blockIdx.x * blockDim.x + threadIdx.x;
    int n    = tid >> 3;
    int lane = tid & 7;
    if (n >= n_vox) return;

    v4f* ov = (v4f*)(out + (size_t)n * C_OUT);

    if (lane >= 4) {
        const v4f* vfr = (const v4f*)(vfeat + (size_t)n * C_LIDAR);
        v4f f = vfr[lane - 4];
        __builtin_nontemporal_store(f, &ov[lane]);
        return;
    }

    int4 c4 = ((const int4*)vcoord)[n];
    int b = c4.x, z = c4.y, y = c4.z, x = c4.w;

    // ---- bit-frozen projection (r17-verified) ----
    float px = (float)x * 0.05f;
    float py = (float)y * 0.05f + -25.6f;
    float pz = (float)z * 0.1f  + -2.0f;

    const float* P = calib + b * 12;
    float pr0 = fmaf(P[3], 1.0f, fmaf(P[2], pz, fmaf(P[1], py, fmaf(P[0], px, 0.0f))));
    float pr1 = fmaf(P[7], 1.0f, fmaf(P[6], pz, fmaf(P[5], py, fmaf(P[4], px, 0.0f))));
    float pr2 = fmaf(P[11], 1.0f, fmaf(P[10], pz, fmaf(P[9], py, fmaf(P[8], px, 0.0f))));

    float inv = 1.0f / pr2;    // CR reciprocal (XLA div->mul rewrite)
    float uf = pr0 * inv;      // plain RN mul
    float vf = pr1 * inv;

    int u = (int)uf;
    int v = (int)vf;
    // ---- end bit-frozen section ----

    bool valid = (u >= 0) & (u < IMG_W) & (v >= 0) & (v < IMG_H);
    int uc = min(max(u, 0), IMG_W - 1);
    int vc = min(max(v, 0), IMG_H - 1);

    const v4f* line = (const v4f*)(ws
        + ((size_t)b * HW + (size_t)vc * IMG_W + uc) * C_IMG);
    v4f g = __builtin_nontemporal_load(&line[lane]);

    v4f r;
    r.x = valid ? g.x : 0.0f;
    r.y = valid ? g.y : 0.0f;
    r.z = valid ? g.z : 0.0f;
    r.w = valid ? g.w : 0.0f;
    __builtin_nontemporal_store(r, &ov[lane]);
}

// Fallback (r18 path) if workspace is too small for the transposed image.
__global__ __launch_bounds__(256) void gather_direct_kernel(
    const float* __restrict__ vfeat,
    const int*   __restrict__ vcoord,
    const float* __restrict__ images,
    const float* __restrict__ calib,
    float*       __restrict__ out,
    int n_vox)
{
    int tid  = blockIdx.x * blockDim.x + threadIdx.x;
    int n    = tid >> 3;
    int lane = tid & 7;
    if (n >= n_vox) return;

    float4* ov = (float4*)(out + (size_t)n * C_OUT);
    if (lane >= 4) {
        const float4* vfr = (const float4*)(vfeat + (size_t)n * C_LIDAR);
        ov[lane] = vfr[lane - 4];
        return;
    }

    int4 c4 = ((const int4*)vcoord)[n];
    int b = c4.x, z = c4.y, y = c4.z, x = c4.w;

    float px = (float)x * 0.05f;
    float py = (float)y * 0.05f + -25.6f;
    float pz = (float)z * 0.1f  + -2.0f;

    const float* P = calib + b * 12;
    float pr0 = fmaf(P[3], 1.0f, fmaf(P[2], pz, fmaf(P[1], py, fmaf(P[0], px, 0.0f))));
    float pr1 = fmaf(P[7], 1.0f, fmaf(P[6], pz, fmaf(P[5], py, fmaf(P[4], px, 0.0f))));
    float pr2 = fmaf(P[11], 1.0f, fmaf(P[10], pz, fmaf(P[9], py, fmaf(P[8], px, 0.0f))));

    float inv = 1.0f / pr2;
    float uf = pr0 * inv;
    float vf = pr1 * inv;
    int u = (int)uf;
    int v = (int)vf;

    bool valid = (u >= 0) & (u < IMG_W) & (v >= 0) & (v < IMG_H);
    int uc = min(max(u, 0), IMG_W - 1);
    int vc = min(max(v, 0), IMG_H - 1);

    const float* ib = images + (size_t)b * (C_IMG * HW)
                             + (size_t)vc * IMG_W + uc
                             + (size_t)(lane * 4) * HW;
    float g0 = ib[0];
    float g1 = ib[(size_t)1 * HW];
    float g2 = ib[(size_t)2 * HW];
    float g3 = ib[(size_t)3 * HW];

    float4 r;
    r.x = valid ? g0 : 0.0f;
    r.y = valid ? g1 : 0.0f;
    r.z = valid ? g2 : 0.0f;
    r.w = valid ? g3 : 0.0f;
    ov[lane] = r;
}

extern "C" void kernel_launch(void* const* d_in, const int* in_sizes, int n_in,
                              void* d_out, int out_size, void* d_ws, size_t ws_size,
                              hipStream_t stream) {
    const float* vfeat  = (const float*)d_in[0];
    const int*   vcoord = (const int*)d_in[1];
    const float* images = (const float*)d_in[2];
    const float* calib  = (const float*)d_in[3];
    float* out = (float*)d_out;

    int n_vox = in_sizes[1] / 4;            // voxel_coords is (N, 4)
    int total_pixels = in_sizes[2] / C_IMG; // B * H * W
    size_t ws_needed = (size_t)total_pixels * C_IMG * sizeof(float);

    long long total = (long long)n_vox * 8;
    dim3 block(256);
    dim3 ggrid((unsigned)((total + 255) / 256));

    if (ws_size >= ws_needed && (total_pixels % TPIX) == 0) {
        float* ws = (float*)d_ws;
        int tiles_total = total_pixels / TPIX;
        dim3 tgrid((unsigned)((tiles_total + 3) / 4));
        transpose_lds_kernel<<<tgrid, block, 0, stream>>>(images, ws, tiles_total);
        gather_kernel<<<ggrid, block, 0, stream>>>(vfeat, vcoord, ws, calib, out, n_vox);
    } else {
        gather_direct_kernel<<<ggrid, block, 0, stream>>>(vfeat, vcoord, images, calib, out, n_vox);
    }
}